// Round 15
// baseline (108.195 us; speedup 1.0000x reference)
//
#include <hip/hip_runtime.h>
#include <math.h>

#define BB 4
#define SS 1024
#define DM 768
#define HH 12
#define DEPTH 64
#define QBLK 8
#define PROWS 16
#define NROWS (BB * SS)   // 4096

typedef float vfloat4 __attribute__((ext_vector_type(4)));
typedef short bf16x8 __attribute__((ext_vector_type(8)));
typedef float f32x4 __attribute__((ext_vector_type(4)));

__device__ inline ushort f2bf(float x) {
    uint u = __float_as_uint(x);
    u += 0x7FFFu + ((u >> 16) & 1u);
    return (ushort)(u >> 16);
}

// ------- Kernel 1: projections. qh f32; kh bf16 row-major; vh bf16 TRANSPOSED -------
__global__ __launch_bounds__(256, 3) void proj_kernel(
    const float* __restrict__ q, const float* __restrict__ k, const float* __restrict__ v,
    const float* __restrict__ Wq, const float* __restrict__ bq,
    const float* __restrict__ Wk, const float* __restrict__ bk,
    const float* __restrict__ Wv, const float* __restrict__ bv,
    float* __restrict__ qh, ushort* __restrict__ khu, ushort* __restrict__ vhT)
{
    __shared__ __align__(16) float rows[PROWS][DM];      // 48 KB
    __shared__ float resT[DEPTH][PROWS + 1];             // 4.25 KB
    const int nrb  = NROWS / PROWS;                      // 256
    const int m    = blockIdx.x / nrb;
    const int rb   = blockIdx.x % nrb;
    const int row0 = rb * PROWS;
    const int t    = threadIdx.x;

    const float* src  = (m == 0) ? q  : (m == 1) ? k  : v;
    const float* W    = (m == 0) ? Wq : (m == 1) ? Wk : Wv;
    const float* bias = (m == 0) ? bq : (m == 1) ? bk : bv;

    const float4* s4 = (const float4*)(src + (size_t)row0 * DM);
    float4* r4 = (float4*)&rows[0][0];
    for (int i = t; i < PROWS * DM / 4; i += 256) r4[i] = s4[i];
    __syncthreads();

    const int d  = t & 63;
    const int rg = t >> 6;                               // 0..3 -> rows rg*4..rg*4+3
    const float* Wp = W + d;
    float a0 = bias[d], a1 = a0, a2 = a0, a3 = a0;
    #pragma unroll 8
    for (int i = 0; i < DM; i += 4) {
        const float wv0 = Wp[(size_t)(i + 0) * DEPTH];
        const float wv1 = Wp[(size_t)(i + 1) * DEPTH];
        const float wv2 = Wp[(size_t)(i + 2) * DEPTH];
        const float wv3 = Wp[(size_t)(i + 3) * DEPTH];
        const float4 r0 = *(const float4*)&rows[rg * 4 + 0][i];
        const float4 r1 = *(const float4*)&rows[rg * 4 + 1][i];
        const float4 r2 = *(const float4*)&rows[rg * 4 + 2][i];
        const float4 r3 = *(const float4*)&rows[rg * 4 + 3][i];
        a0 = fmaf(r0.x, wv0, a0); a0 = fmaf(r0.y, wv1, a0); a0 = fmaf(r0.z, wv2, a0); a0 = fmaf(r0.w, wv3, a0);
        a1 = fmaf(r1.x, wv0, a1); a1 = fmaf(r1.y, wv1, a1); a1 = fmaf(r1.z, wv2, a1); a1 = fmaf(r1.w, wv3, a1);
        a2 = fmaf(r2.x, wv0, a2); a2 = fmaf(r2.y, wv1, a2); a2 = fmaf(r2.z, wv2, a2); a2 = fmaf(r2.w, wv3, a2);
        a3 = fmaf(r3.x, wv0, a3); a3 = fmaf(r3.y, wv1, a3); a3 = fmaf(r3.z, wv2, a3); a3 = fmaf(r3.w, wv3, a3);
    }
    if (m == 2) {
        resT[d][rg * 4 + 0] = a0;
        resT[d][rg * 4 + 1] = a1;
        resT[d][rg * 4 + 2] = a2;
        resT[d][rg * 4 + 3] = a3;
        __syncthreads();
        #pragma unroll
        for (int e = t; e < DEPTH * PROWS; e += 256) {
            const int dd = e >> 4, rr = e & 15;
            vhT[(size_t)dd * NROWS + row0 + rr] = f2bf(resT[dd][rr]);
        }
    } else if (m == 1) {
        ushort* du = khu + (size_t)(row0 + rg * 4) * DEPTH + d;
        du[0] = f2bf(a0); du[DEPTH] = f2bf(a1); du[2 * DEPTH] = f2bf(a2); du[3 * DEPTH] = f2bf(a3);
    } else {
        float* dp = qh + (size_t)(row0 + rg * 4) * DEPTH + d;
        dp[0] = a0; dp[DEPTH] = a1; dp[2 * DEPTH] = a2; dp[3 * DEPTH] = a3;
    }
}

// ---------------- Kernel 2: Wc_red[d][j] = sum_h Wc[h*64+d][j] ----------------
__global__ __launch_bounds__(256) void wcred_kernel(
    const float* __restrict__ Wc, float* __restrict__ Wr)
{
    int idx = blockIdx.x * 256 + threadIdx.x;
    if (idx >= DEPTH * DM) return;
    int d = idx / DM, j = idx % DM;
    float s = 0.f;
    #pragma unroll
    for (int h = 0; h < HH; ++h)
        s += Wc[(size_t)(h * DEPTH + d) * DM + j];
    Wr[idx] = s;
}

// --- Kernel 3: MFMA core; writes only P (bf16, plain stores -> L2) and out ---
__global__ __launch_bounds__(512, 4) void attn_core(
    const float* __restrict__ qh, const ushort* __restrict__ khu, const ushort* __restrict__ vhT,
    const float* __restrict__ Wr, const float* __restrict__ bc,
    float* __restrict__ out, ushort* __restrict__ Pws)
{
    __shared__ __align__(16) ushort qf[16 * 72];         // Q bf16 (scaled), padded
    __shared__ __align__(16) ushort kvbuf[256 * 72];     // K stage / VT[64][264] / part+ohT
    __shared__ __align__(16) ushort pf[16 * 1032];       // P bf16, padded
    __shared__ float redmax[16 * 8];
    __shared__ float redsum[16 * 8];

    const int t = threadIdx.x, l = t & 63, wid = t >> 6;
    const int li = l & 15, g4 = l >> 4;
    const int blk = blockIdx.x, b = blk >> 7;
    const int q0 = (blk & 127) * QBLK;
    const int key = t >> 1, hf = t & 1;                  // K staging role

    // init: qf rows 0-7 = bf16(qh*scale); rows 8-15 = 0; pf rows 8-15 = 0
    {
        const int qq = t >> 6, dd = t & 63;
        qf[qq * 72 + dd] = f2bf(qh[((size_t)b * SS + q0 + qq) * DEPTH + dd] * 0.28867513459481287f);
        for (int i = t; i < 8 * 72; i += 512) qf[8 * 72 + i] = 0;
        for (int i = t; i < 8 * 1032; i += 512) pf[8 * 1032 + i] = 0;
    }

    const ushort* khb = khu + (size_t)b * SS * DEPTH;
    const ushort* vtb = vhT + (size_t)b * SS;            // + d*NROWS + col

    // prefetch K stage 0 (coalesced)
    uint4 kr0, kr1, kr2, kr3;
    {
        const uint4* g = (const uint4*)(khb + (size_t)key * DEPTH + hf * 32);
        kr0 = g[0]; kr1 = g[1]; kr2 = g[2]; kr3 = g[3];
    }
    __syncthreads();

    // A-frags (Q)
    const bf16x8 a0 = *(const bf16x8*)&qf[li * 72 + g4 * 8];
    const bf16x8 a1 = *(const bf16x8*)&qf[li * 72 + 32 + g4 * 8];

    f32x4 c[8];
    #pragma unroll
    for (int i = 0; i < 8; ++i) c[i] = (f32x4){0.f, 0.f, 0.f, 0.f};

    // ---- QK: 4 stages of 256 keys, double-buffered through registers ----
    #pragma unroll
    for (int s = 0; s < 4; ++s) {
        if (s) __syncthreads();
        {
            uint4* d4 = (uint4*)&kvbuf[key * 72 + hf * 32];
            d4[0] = kr0; d4[1] = kr1; d4[2] = kr2; d4[3] = kr3;
        }
        if (s < 3) {
            const uint4* g = (const uint4*)(khb + (size_t)((s + 1) * 256 + key) * DEPTH + hf * 32);
            kr0 = g[0]; kr1 = g[1]; kr2 = g[2]; kr3 = g[3];
        }
        __syncthreads();
        __builtin_amdgcn_s_setprio(1);
        #pragma unroll
        for (int jj = 0; jj < 2; ++jj) {
            const int tl = wid + 8 * jj;
            const int ci = 2 * s + jj;
            const bf16x8 b0 = *(const bf16x8*)&kvbuf[(tl * 16 + li) * 72 + g4 * 8];
            const bf16x8 b1 = *(const bf16x8*)&kvbuf[(tl * 16 + li) * 72 + 32 + g4 * 8];
            c[ci] = __builtin_amdgcn_mfma_f32_16x16x32_bf16(a0, b0, c[ci], 0, 0, 0);
            c[ci] = __builtin_amdgcn_mfma_f32_16x16x32_bf16(a1, b1, c[ci], 0, 0, 0);
        }
        __builtin_amdgcn_s_setprio(0);
    }

    // V staging roles: row vrow, 16B col
    const int vrow = t >> 5;                             // 0..15
    const int vcol = (t & 31) * 8;                       // ushort col, 16B aligned
    // prefetch V stage 0 (coalesced from vhT; hides under softmax)
    uint4 vp0, vp1, vp2, vp3;
    {
        vp0 = *(const uint4*)(vtb + (size_t)(0 * 16 + vrow) * NROWS + vcol);
        vp1 = *(const uint4*)(vtb + (size_t)(1 * 16 + vrow) * NROWS + vcol);
        vp2 = *(const uint4*)(vtb + (size_t)(2 * 16 + vrow) * NROWS + vcol);
        vp3 = *(const uint4*)(vtb + (size_t)(3 * 16 + vrow) * NROWS + vcol);
    }

    // ---- softmax on C-frags: row = 4*g4+reg, col = tile*16+li ----
    float mx[4], sm[4], inv[4];
    #pragma unroll
    for (int r = 0; r < 4; ++r) {
        float m_ = c[0][r];
        #pragma unroll
        for (int i = 1; i < 8; ++i) m_ = fmaxf(m_, c[i][r]);
        #pragma unroll
        for (int off = 1; off < 16; off <<= 1) m_ = fmaxf(m_, __shfl_xor(m_, off));
        mx[r] = m_;
    }
    if (li == 0) {
        #pragma unroll
        for (int r = 0; r < 4; ++r) redmax[(4 * g4 + r) * 8 + wid] = mx[r];
    }
    __syncthreads();
    #pragma unroll
    for (int r = 0; r < 4; ++r) {
        float m_ = redmax[(4 * g4 + r) * 8];
        #pragma unroll
        for (int w2 = 1; w2 < 8; ++w2) m_ = fmaxf(m_, redmax[(4 * g4 + r) * 8 + w2]);
        mx[r] = m_;
        sm[r] = 0.f;
    }
    #pragma unroll
    for (int i = 0; i < 8; ++i) {
        #pragma unroll
        for (int r = 0; r < 4; ++r) {
            const float e = __expf(c[i][r] - mx[r]);
            c[i][r] = e;
            sm[r] += e;
        }
    }
    #pragma unroll
    for (int r = 0; r < 4; ++r) {
        float s_ = sm[r];
        #pragma unroll
        for (int off = 1; off < 16; off <<= 1) s_ += __shfl_xor(s_, off);
        sm[r] = s_;
    }
    if (li == 0) {
        #pragma unroll
        for (int r = 0; r < 4; ++r) redsum[(4 * g4 + r) * 8 + wid] = sm[r];
    }
    __syncthreads();
    #pragma unroll
    for (int r = 0; r < 4; ++r) {
        float s_ = 0.f;
        #pragma unroll
        for (int w2 = 0; w2 < 8; ++w2) s_ += redsum[(4 * g4 + r) * 8 + w2];
        inv[r] = 1.f / s_;
    }
    // write P (bf16) rows 0-7 to pf
    if (l < 32) {
        #pragma unroll
        for (int i = 0; i < 8; ++i) {
            const int colbase = (16 * (i >> 1) + wid + 8 * (i & 1)) * 16 + li;
            #pragma unroll
            for (int r = 0; r < 4; ++r)
                pf[(4 * g4 + r) * 1032 + colbase] = f2bf(c[i][r] * inv[r]);
        }
    }
    __syncthreads();

    // ---- P rows -> workspace (plain stores; stays L2-resident for expand) ----
    {
        const int qq = t >> 6, c0 = t & 63;
        const int col = c0 * 16;                         // 16 ushorts = 32 B per thread
        const ushort* prow = &pf[qq * 1032];
        ushort* pws = Pws + ((size_t)b * SS + q0 + qq) * SS;
        *(uint4*)&pws[col]     = *(const uint4*)&prow[col];
        *(uint4*)&pws[col + 8] = *(const uint4*)&prow[col + 8];
    }

    // ---- PV: 4 stages; V staged via conflict-free b128 writes from vhT ----
    f32x4 cp = {0.f, 0.f, 0.f, 0.f};
    const int dt = wid >> 1, par = wid & 1;
    ushort* VT = kvbuf;                                  // [64][264]
    #pragma unroll
    for (int s = 0; s < 4; ++s) {
        if (s) __syncthreads();
        {
            *(uint4*)&VT[(0 * 16 + vrow) * 264 + vcol] = vp0;
            *(uint4*)&VT[(1 * 16 + vrow) * 264 + vcol] = vp1;
            *(uint4*)&VT[(2 * 16 + vrow) * 264 + vcol] = vp2;
            *(uint4*)&VT[(3 * 16 + vrow) * 264 + vcol] = vp3;
        }
        if (s < 3) {
            const int sc = (s + 1) * 256;
            vp0 = *(const uint4*)(vtb + (size_t)(0 * 16 + vrow) * NROWS + sc + vcol);
            vp1 = *(const uint4*)(vtb + (size_t)(1 * 16 + vrow) * NROWS + sc + vcol);
            vp2 = *(const uint4*)(vtb + (size_t)(2 * 16 + vrow) * NROWS + sc + vcol);
            vp3 = *(const uint4*)(vtb + (size_t)(3 * 16 + vrow) * NROWS + sc + vcol);
        }
        __syncthreads();
        __builtin_amdgcn_s_setprio(1);
        #pragma unroll
        for (int c2 = 0; c2 < 4; ++c2) {
            const int cc = par + 2 * c2;
            const bf16x8 ap = *(const bf16x8*)&pf[li * 1032 + s * 256 + cc * 32 + g4 * 8];
            const bf16x8 bv = *(const bf16x8*)&VT[(dt * 16 + li) * 264 + cc * 32 + g4 * 8];
            cp = __builtin_amdgcn_mfma_f32_16x16x32_bf16(ap, bv, cp, 0, 0, 0);
        }
        __builtin_amdgcn_s_setprio(0);
    }
    __syncthreads();

    // ---- reduce parity pairs -> ohT[64][12] ----
    float* part_f = (float*)kvbuf;                       // [8][256]
    float* ohT_f  = ((float*)kvbuf) + 2048;              // [64][12]
    #pragma unroll
    for (int r = 0; r < 4; ++r) part_f[wid * 256 + r * 64 + l] = cp[r];
    __syncthreads();
    {
        const int qq = t >> 6, dd = t & 63;
        const int ls = (qq >> 2) * 16 + (dd & 15), rr = qq & 3, w0 = (dd >> 4) * 2;
        ohT_f[dd * 12 + qq] = part_f[w0 * 256 + rr * 64 + ls] + part_f[(w0 + 1) * 256 + rr * 64 + ls];
    }
    __syncthreads();

    // ---- out rows = ohT @ Wr + bc ----
    for (int j = t; j < DM; j += 512) {
        float a[QBLK];
        const float bj = bc[j];
        #pragma unroll
        for (int r = 0; r < QBLK; ++r) a[r] = bj;
        const float* wc = Wr + j;
        #pragma unroll 16
        for (int d2 = 0; d2 < DEPTH; ++d2) {
            const float wv = wc[(size_t)d2 * DM];
            const float4 o0 = *(const float4*)&ohT_f[d2 * 12];
            const float4 o1 = *(const float4*)&ohT_f[d2 * 12 + 4];
            a[0] = fmaf(o0.x, wv, a[0]); a[1] = fmaf(o0.y, wv, a[1]);
            a[2] = fmaf(o0.z, wv, a[2]); a[3] = fmaf(o0.w, wv, a[3]);
            a[4] = fmaf(o1.x, wv, a[4]); a[5] = fmaf(o1.y, wv, a[5]);
            a[6] = fmaf(o1.z, wv, a[6]); a[7] = fmaf(o1.w, wv, a[7]);
        }
        float* ob = out + ((size_t)b * SS + q0) * DM + j;
        #pragma unroll
        for (int r = 0; r < QBLK; ++r)
            __builtin_nontemporal_store(a[r], ob + (size_t)r * DM);
    }
}

// ---- Kernel 4: expand P (bf16, L2-resident) -> 12 fp32 head copies (pure streaming) ----
#define EROWS 2
__global__ __launch_bounds__(256) void expand_kernel(
    const ushort* __restrict__ Pws, float* __restrict__ attn)
{
    const int t = threadIdx.x;
    #pragma unroll
    for (int r = 0; r < EROWS; ++r) {
        const int gr = blockIdx.x * EROWS + r;           // 0 .. B*S-1
        const int b  = gr >> 10;
        const int qi = gr & (SS - 1);
        const ushort* prow = Pws + (size_t)gr * SS;
        const int col = t * 4;
        vfloat4 v4;
        v4.x = __uint_as_float((uint)prow[col + 0] << 16);
        v4.y = __uint_as_float((uint)prow[col + 1] << 16);
        v4.z = __uint_as_float((uint)prow[col + 2] << 16);
        v4.w = __uint_as_float((uint)prow[col + 3] << 16);
        float* abase = attn + (((size_t)b * HH) * SS + qi) * SS;
        #pragma unroll
        for (int h = 0; h < HH; ++h)
            __builtin_nontemporal_store(v4, (vfloat4*)(abase + (size_t)h * SS * SS + col));
    }
}

extern "C" void kernel_launch(void* const* d_in, const int* in_sizes, int n_in,
                              void* d_out, int out_size, void* d_ws, size_t ws_size,
                              hipStream_t stream) {
    const float* q  = (const float*)d_in[0];
    const float* k  = (const float*)d_in[1];
    const float* v  = (const float*)d_in[2];
    const float* Wq = (const float*)d_in[3];
    const float* bq = (const float*)d_in[4];
    const float* Wk = (const float*)d_in[5];
    const float* bk = (const float*)d_in[6];
    const float* Wv = (const float*)d_in[7];
    const float* bv = (const float*)d_in[8];
    const float* Wc = (const float*)d_in[9];
    const float* bc = (const float*)d_in[10];

    float* out  = (float*)d_out;                              // [B,S,DM]
    float* attn = out + (size_t)BB * SS * DM;                 // [B,H,S,S]

    float* ws = (float*)d_ws;
    const size_t NPROJ = (size_t)NROWS * DEPTH;               // 262144
    float* qh   = ws;                                         // f32
    ushort* khu = (ushort*)(ws + NPROJ);                      // bf16 row-major
    ushort* vhT = (ushort*)(ws + NPROJ + NPROJ / 2);          // bf16 transposed [DEPTH][NROWS]
    float* Wr   = ws + 2 * NPROJ;                             // 64*768 f32
    ushort* Pws = (ushort*)(ws + 2 * NPROJ + DEPTH * DM);     // bf16 [B*S][S] = 8.4 MB

    wcred_kernel<<<(DEPTH * DM + 255) / 256, 256, 0, stream>>>(Wc, Wr);
    proj_kernel<<<3 * (NROWS / PROWS), 256, 0, stream>>>(q, k, v, Wq, bq, Wk, bk, Wv, bv, qh, khu, vhT);
    attn_core<<<BB * (SS / QBLK), 512, 0, stream>>>(qh, khu, vhT, Wr, bc, out, Pws);
    expand_kernel<<<NROWS / EROWS, 256, 0, stream>>>(Pws, attn);
}

// Round 16
// 101.821 us; speedup vs baseline: 1.0626x; 1.0626x over previous
//
#include <hip/hip_runtime.h>
#include <math.h>

#define BB 4
#define SS 1024
#define DM 768
#define HH 12
#define DEPTH 64
#define QBLK 8
#define PROWS 16
#define NROWS (BB * SS)   // 4096

// LDS-only barrier: waits LDS ops, NOT outstanding global loads (they target regs).
#define LBAR() asm volatile("s_waitcnt lgkmcnt(0)\n\ts_barrier" ::: "memory")

typedef float vfloat4 __attribute__((ext_vector_type(4)));
typedef short bf16x8 __attribute__((ext_vector_type(8)));
typedef float f32x4 __attribute__((ext_vector_type(4)));

__device__ inline ushort f2bf(float x) {
    uint u = __float_as_uint(x);
    u += 0x7FFFu + ((u >> 16) & 1u);
    return (ushort)(u >> 16);
}

// ------- Kernel 1: projections. qh f32; kh bf16 row-major; vh bf16 TRANSPOSED -------
__global__ __launch_bounds__(256, 3) void proj_kernel(
    const float* __restrict__ q, const float* __restrict__ k, const float* __restrict__ v,
    const float* __restrict__ Wq, const float* __restrict__ bq,
    const float* __restrict__ Wk, const float* __restrict__ bk,
    const float* __restrict__ Wv, const float* __restrict__ bv,
    float* __restrict__ qh, ushort* __restrict__ khu, ushort* __restrict__ vhT)
{
    __shared__ __align__(16) float rows[PROWS][DM];      // 48 KB
    __shared__ float resT[DEPTH][PROWS + 1];             // 4.25 KB
    const int nrb  = NROWS / PROWS;                      // 256
    const int m    = blockIdx.x / nrb;
    const int rb   = blockIdx.x % nrb;
    const int row0 = rb * PROWS;
    const int t    = threadIdx.x;

    const float* src  = (m == 0) ? q  : (m == 1) ? k  : v;
    const float* W    = (m == 0) ? Wq : (m == 1) ? Wk : Wv;
    const float* bias = (m == 0) ? bq : (m == 1) ? bk : bv;

    const float4* s4 = (const float4*)(src + (size_t)row0 * DM);
    float4* r4 = (float4*)&rows[0][0];
    for (int i = t; i < PROWS * DM / 4; i += 256) r4[i] = s4[i];
    __syncthreads();

    const int d  = t & 63;
    const int rg = t >> 6;                               // 0..3 -> rows rg*4..rg*4+3
    const float* Wp = W + d;
    float a0 = bias[d], a1 = a0, a2 = a0, a3 = a0;
    #pragma unroll 8
    for (int i = 0; i < DM; i += 4) {
        const float wv0 = Wp[(size_t)(i + 0) * DEPTH];
        const float wv1 = Wp[(size_t)(i + 1) * DEPTH];
        const float wv2 = Wp[(size_t)(i + 2) * DEPTH];
        const float wv3 = Wp[(size_t)(i + 3) * DEPTH];
        const float4 r0 = *(const float4*)&rows[rg * 4 + 0][i];
        const float4 r1 = *(const float4*)&rows[rg * 4 + 1][i];
        const float4 r2 = *(const float4*)&rows[rg * 4 + 2][i];
        const float4 r3 = *(const float4*)&rows[rg * 4 + 3][i];
        a0 = fmaf(r0.x, wv0, a0); a0 = fmaf(r0.y, wv1, a0); a0 = fmaf(r0.z, wv2, a0); a0 = fmaf(r0.w, wv3, a0);
        a1 = fmaf(r1.x, wv0, a1); a1 = fmaf(r1.y, wv1, a1); a1 = fmaf(r1.z, wv2, a1); a1 = fmaf(r1.w, wv3, a1);
        a2 = fmaf(r2.x, wv0, a2); a2 = fmaf(r2.y, wv1, a2); a2 = fmaf(r2.z, wv2, a2); a2 = fmaf(r2.w, wv3, a2);
        a3 = fmaf(r3.x, wv0, a3); a3 = fmaf(r3.y, wv1, a3); a3 = fmaf(r3.z, wv2, a3); a3 = fmaf(r3.w, wv3, a3);
    }
    if (m == 2) {
        resT[d][rg * 4 + 0] = a0;
        resT[d][rg * 4 + 1] = a1;
        resT[d][rg * 4 + 2] = a2;
        resT[d][rg * 4 + 3] = a3;
        __syncthreads();
        #pragma unroll
        for (int e = t; e < DEPTH * PROWS; e += 256) {
            const int dd = e >> 4, rr = e & 15;
            vhT[(size_t)dd * NROWS + row0 + rr] = f2bf(resT[dd][rr]);
        }
    } else if (m == 1) {
        ushort* du = khu + (size_t)(row0 + rg * 4) * DEPTH + d;
        du[0] = f2bf(a0); du[DEPTH] = f2bf(a1); du[2 * DEPTH] = f2bf(a2); du[3 * DEPTH] = f2bf(a3);
    } else {
        float* dp = qh + (size_t)(row0 + rg * 4) * DEPTH + d;
        dp[0] = a0; dp[DEPTH] = a1; dp[2 * DEPTH] = a2; dp[3 * DEPTH] = a3;
    }
}

// ---------------- Kernel 2: Wc_red[d][j] = sum_h Wc[h*64+d][j] ----------------
__global__ __launch_bounds__(256) void wcred_kernel(
    const float* __restrict__ Wc, float* __restrict__ Wr)
{
    int idx = blockIdx.x * 256 + threadIdx.x;
    if (idx >= DEPTH * DM) return;
    int d = idx / DM, j = idx % DM;
    float s = 0.f;
    #pragma unroll
    for (int h = 0; h < HH; ++h)
        s += Wc[(size_t)(h * DEPTH + d) * DM + j];
    Wr[idx] = s;
}

// --- Kernel 3: MFMA core; all in-core barriers are lgkmcnt-only (loads stay in flight) ---
__global__ __launch_bounds__(512, 4) void attn_core(
    const float* __restrict__ qh, const ushort* __restrict__ khu, const ushort* __restrict__ vhT,
    const float* __restrict__ Wr, const float* __restrict__ bc,
    float* __restrict__ out, float* __restrict__ attn)
{
    __shared__ __align__(16) ushort qf[16 * 72];         // Q bf16 (scaled), padded
    __shared__ __align__(16) ushort kvbuf[256 * 72];     // K stage / VT[64][264] / part+ohT
    __shared__ __align__(16) ushort pf[16 * 1032];       // P bf16, padded
    __shared__ float redmax[16 * 8];
    __shared__ float redsum[16 * 8];

    const int t = threadIdx.x, l = t & 63, wid = t >> 6;
    const int li = l & 15, g4 = l >> 4;
    const int blk = blockIdx.x, b = blk >> 7;
    const int q0 = (blk & 127) * QBLK;
    const int key = t >> 1, hf = t & 1;                  // K staging role

    // init: qf rows 0-7 = bf16(qh*scale); rows 8-15 = 0; pf rows 8-15 = 0
    {
        const int qq = t >> 6, dd = t & 63;
        qf[qq * 72 + dd] = f2bf(qh[((size_t)b * SS + q0 + qq) * DEPTH + dd] * 0.28867513459481287f);
        for (int i = t; i < 8 * 72; i += 512) qf[8 * 72 + i] = 0;
        for (int i = t; i < 8 * 1032; i += 512) pf[8 * 1032 + i] = 0;
    }

    const ushort* khb = khu + (size_t)b * SS * DEPTH;
    const ushort* vtb = vhT + (size_t)b * SS;            // + d*NROWS + col

    // prefetch K stage 0 (coalesced)
    uint4 kr0, kr1, kr2, kr3;
    {
        const uint4* g = (const uint4*)(khb + (size_t)key * DEPTH + hf * 32);
        kr0 = g[0]; kr1 = g[1]; kr2 = g[2]; kr3 = g[3];
    }
    LBAR();

    // A-frags (Q)
    const bf16x8 a0 = *(const bf16x8*)&qf[li * 72 + g4 * 8];
    const bf16x8 a1 = *(const bf16x8*)&qf[li * 72 + 32 + g4 * 8];

    f32x4 c[8];
    #pragma unroll
    for (int i = 0; i < 8; ++i) c[i] = (f32x4){0.f, 0.f, 0.f, 0.f};

    // ---- QK: 4 stages of 256 keys; prefetch loads stay in flight across barriers ----
    #pragma unroll
    for (int s = 0; s < 4; ++s) {
        if (s) LBAR();                                   // prev stage ds_reads done
        {
            uint4* d4 = (uint4*)&kvbuf[key * 72 + hf * 32];
            d4[0] = kr0; d4[1] = kr1; d4[2] = kr2; d4[3] = kr3;
        }
        if (s < 3) {                                     // issue next-stage loads; NOT drained at barrier
            const uint4* g = (const uint4*)(khb + (size_t)((s + 1) * 256 + key) * DEPTH + hf * 32);
            kr0 = g[0]; kr1 = g[1]; kr2 = g[2]; kr3 = g[3];
        }
        LBAR();                                          // ds_writes visible
        __builtin_amdgcn_s_setprio(1);
        #pragma unroll
        for (int jj = 0; jj < 2; ++jj) {
            const int tl = wid + 8 * jj;
            const int ci = 2 * s + jj;
            const bf16x8 b0 = *(const bf16x8*)&kvbuf[(tl * 16 + li) * 72 + g4 * 8];
            const bf16x8 b1 = *(const bf16x8*)&kvbuf[(tl * 16 + li) * 72 + 32 + g4 * 8];
            c[ci] = __builtin_amdgcn_mfma_f32_16x16x32_bf16(a0, b0, c[ci], 0, 0, 0);
            c[ci] = __builtin_amdgcn_mfma_f32_16x16x32_bf16(a1, b1, c[ci], 0, 0, 0);
        }
        __builtin_amdgcn_s_setprio(0);
    }

    // V staging roles: row vrow, 16B col
    const int vrow = t >> 5;                             // 0..15
    const int vcol = (t & 31) * 8;                       // ushort col, 16B aligned
    // prefetch V stage 0 (in flight under softmax)
    uint4 vp0, vp1, vp2, vp3;
    {
        vp0 = *(const uint4*)(vtb + (size_t)(0 * 16 + vrow) * NROWS + vcol);
        vp1 = *(const uint4*)(vtb + (size_t)(1 * 16 + vrow) * NROWS + vcol);
        vp2 = *(const uint4*)(vtb + (size_t)(2 * 16 + vrow) * NROWS + vcol);
        vp3 = *(const uint4*)(vtb + (size_t)(3 * 16 + vrow) * NROWS + vcol);
    }

    // ---- softmax on C-frags: row = 4*g4+reg, col = tile*16+li ----
    float mx[4], sm[4], inv[4];
    #pragma unroll
    for (int r = 0; r < 4; ++r) {
        float m_ = c[0][r];
        #pragma unroll
        for (int i = 1; i < 8; ++i) m_ = fmaxf(m_, c[i][r]);
        #pragma unroll
        for (int off = 1; off < 16; off <<= 1) m_ = fmaxf(m_, __shfl_xor(m_, off));
        mx[r] = m_;
    }
    if (li == 0) {
        #pragma unroll
        for (int r = 0; r < 4; ++r) redmax[(4 * g4 + r) * 8 + wid] = mx[r];
    }
    LBAR();
    #pragma unroll
    for (int r = 0; r < 4; ++r) {
        float m_ = redmax[(4 * g4 + r) * 8];
        #pragma unroll
        for (int w2 = 1; w2 < 8; ++w2) m_ = fmaxf(m_, redmax[(4 * g4 + r) * 8 + w2]);
        mx[r] = m_;
        sm[r] = 0.f;
    }
    #pragma unroll
    for (int i = 0; i < 8; ++i) {
        #pragma unroll
        for (int r = 0; r < 4; ++r) {
            const float e = __expf(c[i][r] - mx[r]);
            c[i][r] = e;
            sm[r] += e;
        }
    }
    #pragma unroll
    for (int r = 0; r < 4; ++r) {
        float s_ = sm[r];
        #pragma unroll
        for (int off = 1; off < 16; off <<= 1) s_ += __shfl_xor(s_, off);
        sm[r] = s_;
    }
    if (li == 0) {
        #pragma unroll
        for (int r = 0; r < 4; ++r) redsum[(4 * g4 + r) * 8 + wid] = sm[r];
    }
    LBAR();
    #pragma unroll
    for (int r = 0; r < 4; ++r) {
        float s_ = 0.f;
        #pragma unroll
        for (int w2 = 0; w2 < 8; ++w2) s_ += redsum[(4 * g4 + r) * 8 + w2];
        inv[r] = 1.f / s_;
    }
    // write P (bf16) rows 0-7 to pf
    if (l < 32) {
        #pragma unroll
        for (int i = 0; i < 8; ++i) {
            const int colbase = (16 * (i >> 1) + wid + 8 * (i & 1)) * 16 + li;
            #pragma unroll
            for (int r = 0; r < 4; ++r)
                pf[(4 * g4 + r) * 1032 + colbase] = f2bf(c[i][r] * inv[r]);
        }
    }
    LBAR();

    // ---- PV: 4 stages; V staged via conflict-free b128 writes from vhT ----
    f32x4 cp = {0.f, 0.f, 0.f, 0.f};
    const int dt = wid >> 1, par = wid & 1;
    ushort* VT = kvbuf;                                  // [64][264]
    #pragma unroll
    for (int s = 0; s < 4; ++s) {
        if (s) LBAR();
        {
            *(uint4*)&VT[(0 * 16 + vrow) * 264 + vcol] = vp0;
            *(uint4*)&VT[(1 * 16 + vrow) * 264 + vcol] = vp1;
            *(uint4*)&VT[(2 * 16 + vrow) * 264 + vcol] = vp2;
            *(uint4*)&VT[(3 * 16 + vrow) * 264 + vcol] = vp3;
        }
        if (s < 3) {                                     // in flight across barriers
            const int sc = (s + 1) * 256;
            vp0 = *(const uint4*)(vtb + (size_t)(0 * 16 + vrow) * NROWS + sc + vcol);
            vp1 = *(const uint4*)(vtb + (size_t)(1 * 16 + vrow) * NROWS + sc + vcol);
            vp2 = *(const uint4*)(vtb + (size_t)(2 * 16 + vrow) * NROWS + sc + vcol);
            vp3 = *(const uint4*)(vtb + (size_t)(3 * 16 + vrow) * NROWS + sc + vcol);
        }
        LBAR();
        __builtin_amdgcn_s_setprio(1);
        #pragma unroll
        for (int c2 = 0; c2 < 4; ++c2) {
            const int cc = par + 2 * c2;
            const bf16x8 ap = *(const bf16x8*)&pf[li * 1032 + s * 256 + cc * 32 + g4 * 8];
            const bf16x8 bv = *(const bf16x8*)&VT[(dt * 16 + li) * 264 + cc * 32 + g4 * 8];
            cp = __builtin_amdgcn_mfma_f32_16x16x32_bf16(ap, bv, cp, 0, 0, 0);
        }
        __builtin_amdgcn_s_setprio(0);
    }
    LBAR();

    // ---- reduce parity pairs -> ohT[64][12] ----
    float* part_f = (float*)kvbuf;                       // [8][256]
    float* ohT_f  = ((float*)kvbuf) + 2048;              // [64][12]
    #pragma unroll
    for (int r = 0; r < 4; ++r) part_f[wid * 256 + r * 64 + l] = cp[r];
    LBAR();
    {
        const int qq = t >> 6, dd = t & 63;
        const int ls = (qq >> 2) * 16 + (dd & 15), rr = qq & 3, w0 = (dd >> 4) * 2;
        ohT_f[dd * 12 + qq] = part_f[w0 * 256 + rr * 64 + ls] + part_f[(w0 + 1) * 256 + rr * 64 + ls];
    }
    LBAR();

    // ---- out rows = ohT @ Wr + bc ----
    for (int j = t; j < DM; j += 512) {
        float a[QBLK];
        const float bj = bc[j];
        #pragma unroll
        for (int r = 0; r < QBLK; ++r) a[r] = bj;
        const float* wc = Wr + j;
        #pragma unroll 16
        for (int d2 = 0; d2 < DEPTH; ++d2) {
            const float wv = wc[(size_t)d2 * DM];
            const float4 o0 = *(const float4*)&ohT_f[d2 * 12];
            const float4 o1 = *(const float4*)&ohT_f[d2 * 12 + 4];
            a[0] = fmaf(o0.x, wv, a[0]); a[1] = fmaf(o0.y, wv, a[1]);
            a[2] = fmaf(o0.z, wv, a[2]); a[3] = fmaf(o0.w, wv, a[3]);
            a[4] = fmaf(o1.x, wv, a[4]); a[5] = fmaf(o1.y, wv, a[5]);
            a[6] = fmaf(o1.z, wv, a[6]); a[7] = fmaf(o1.w, wv, a[7]);
        }
        float* ob = out + ((size_t)b * SS + q0) * DM + j;
        #pragma unroll
        for (int r = 0; r < QBLK; ++r)
            __builtin_nontemporal_store(a[r], ob + (size_t)r * DM);
    }

    // ---- 12-head weight burst LAST (fire-and-forget; drains past s_endpgm) ----
    {
        const int qq = t >> 6, c0 = t & 63;
        const ushort* prow = &pf[qq * 1032];
        float* abase = attn + ((size_t)(b * HH) * SS + (q0 + qq)) * SS;
        #pragma unroll
        for (int i = 0; i < 4; ++i) {
            const int col = i * 256 + c0 * 4;
            vfloat4 v4;
            v4.x = __uint_as_float((uint)prow[col + 0] << 16);
            v4.y = __uint_as_float((uint)prow[col + 1] << 16);
            v4.z = __uint_as_float((uint)prow[col + 2] << 16);
            v4.w = __uint_as_float((uint)prow[col + 3] << 16);
            #pragma unroll
            for (int h = 0; h < HH; ++h)
                __builtin_nontemporal_store(v4, (vfloat4*)(abase + (size_t)h * SS * SS + col));
        }
    }
}

extern "C" void kernel_launch(void* const* d_in, const int* in_sizes, int n_in,
                              void* d_out, int out_size, void* d_ws, size_t ws_size,
                              hipStream_t stream) {
    const float* q  = (const float*)d_in[0];
    const float* k  = (const float*)d_in[1];
    const float* v  = (const float*)d_in[2];
    const float* Wq = (const float*)d_in[3];
    const float* bq = (const float*)d_in[4];
    const float* Wk = (const float*)d_in[5];
    const float* bk = (const float*)d_in[6];
    const float* Wv = (const float*)d_in[7];
    const float* bv = (const float*)d_in[8];
    const float* Wc = (const float*)d_in[9];
    const float* bc = (const float*)d_in[10];

    float* out  = (float*)d_out;                              // [B,S,DM]
    float* attn = out + (size_t)BB * SS * DM;                 // [B,H,S,S]

    float* ws = (float*)d_ws;
    const size_t NPROJ = (size_t)NROWS * DEPTH;               // 262144
    float* qh   = ws;                                         // f32
    ushort* khu = (ushort*)(ws + NPROJ);                      // bf16 row-major
    ushort* vhT = (ushort*)(ws + NPROJ + NPROJ / 2);          // bf16 transposed [DEPTH][NROWS]
    float* Wr   = ws + 2 * NPROJ;                             // 64*768 f32

    wcred_kernel<<<(DEPTH * DM + 255) / 256, 256, 0, stream>>>(Wc, Wr);
    proj_kernel<<<3 * (NROWS / PROWS), 256, 0, stream>>>(q, k, v, Wq, bq, Wk, bk, Wv, bv, qh, khu, vhT);
    attn_core<<<BB * (SS / QBLK), 512, 0, stream>>>(qh, khu, vhT, Wr, bc, out, attn);
}

// Round 17
// 100.689 us; speedup vs baseline: 1.0745x; 1.0112x over previous
//
#include <hip/hip_runtime.h>
#include <math.h>

#define BB 4
#define SS 1024
#define DM 768
#define HH 12
#define DEPTH 64
#define QBLK 8
#define PROWS 16
#define NROWS (BB * SS)   // 4096

// LDS-only barrier: waits LDS ops, NOT outstanding global loads/stores.
#define LBAR() asm volatile("s_waitcnt lgkmcnt(0)\n\ts_barrier" ::: "memory")

typedef float vfloat4 __attribute__((ext_vector_type(4)));
typedef short bf16x8 __attribute__((ext_vector_type(8)));
typedef float f32x4 __attribute__((ext_vector_type(4)));

__device__ inline ushort f2bf(float x) {
    uint u = __float_as_uint(x);
    u += 0x7FFFu + ((u >> 16) & 1u);
    return (ushort)(u >> 16);
}

// ------- Kernel 1: projections. qh f32; kh bf16 row-major; vh bf16 TRANSPOSED -------
__global__ __launch_bounds__(256, 3) void proj_kernel(
    const float* __restrict__ q, const float* __restrict__ k, const float* __restrict__ v,
    const float* __restrict__ Wq, const float* __restrict__ bq,
    const float* __restrict__ Wk, const float* __restrict__ bk,
    const float* __restrict__ Wv, const float* __restrict__ bv,
    float* __restrict__ qh, ushort* __restrict__ khu, ushort* __restrict__ vhT)
{
    __shared__ __align__(16) float rows[PROWS][DM];      // 48 KB
    __shared__ float resT[DEPTH][PROWS + 1];             // 4.25 KB
    const int nrb  = NROWS / PROWS;                      // 256
    const int m    = blockIdx.x / nrb;
    const int rb   = blockIdx.x % nrb;
    const int row0 = rb * PROWS;
    const int t    = threadIdx.x;

    const float* src  = (m == 0) ? q  : (m == 1) ? k  : v;
    const float* W    = (m == 0) ? Wq : (m == 1) ? Wk : Wv;
    const float* bias = (m == 0) ? bq : (m == 1) ? bk : bv;

    const float4* s4 = (const float4*)(src + (size_t)row0 * DM);
    float4* r4 = (float4*)&rows[0][0];
    for (int i = t; i < PROWS * DM / 4; i += 256) r4[i] = s4[i];
    __syncthreads();

    const int d  = t & 63;
    const int rg = t >> 6;                               // 0..3 -> rows rg*4..rg*4+3
    const float* Wp = W + d;
    float a0 = bias[d], a1 = a0, a2 = a0, a3 = a0;
    #pragma unroll 8
    for (int i = 0; i < DM; i += 4) {
        const float wv0 = Wp[(size_t)(i + 0) * DEPTH];
        const float wv1 = Wp[(size_t)(i + 1) * DEPTH];
        const float wv2 = Wp[(size_t)(i + 2) * DEPTH];
        const float wv3 = Wp[(size_t)(i + 3) * DEPTH];
        const float4 r0 = *(const float4*)&rows[rg * 4 + 0][i];
        const float4 r1 = *(const float4*)&rows[rg * 4 + 1][i];
        const float4 r2 = *(const float4*)&rows[rg * 4 + 2][i];
        const float4 r3 = *(const float4*)&rows[rg * 4 + 3][i];
        a0 = fmaf(r0.x, wv0, a0); a0 = fmaf(r0.y, wv1, a0); a0 = fmaf(r0.z, wv2, a0); a0 = fmaf(r0.w, wv3, a0);
        a1 = fmaf(r1.x, wv0, a1); a1 = fmaf(r1.y, wv1, a1); a1 = fmaf(r1.z, wv2, a1); a1 = fmaf(r1.w, wv3, a1);
        a2 = fmaf(r2.x, wv0, a2); a2 = fmaf(r2.y, wv1, a2); a2 = fmaf(r2.z, wv2, a2); a2 = fmaf(r2.w, wv3, a2);
        a3 = fmaf(r3.x, wv0, a3); a3 = fmaf(r3.y, wv1, a3); a3 = fmaf(r3.z, wv2, a3); a3 = fmaf(r3.w, wv3, a3);
    }
    if (m == 2) {
        resT[d][rg * 4 + 0] = a0;
        resT[d][rg * 4 + 1] = a1;
        resT[d][rg * 4 + 2] = a2;
        resT[d][rg * 4 + 3] = a3;
        __syncthreads();
        #pragma unroll
        for (int e = t; e < DEPTH * PROWS; e += 256) {
            const int dd = e >> 4, rr = e & 15;
            vhT[(size_t)dd * NROWS + row0 + rr] = f2bf(resT[dd][rr]);
        }
    } else if (m == 1) {
        ushort* du = khu + (size_t)(row0 + rg * 4) * DEPTH + d;
        du[0] = f2bf(a0); du[DEPTH] = f2bf(a1); du[2 * DEPTH] = f2bf(a2); du[3 * DEPTH] = f2bf(a3);
    } else {
        float* dp = qh + (size_t)(row0 + rg * 4) * DEPTH + d;
        dp[0] = a0; dp[DEPTH] = a1; dp[2 * DEPTH] = a2; dp[3 * DEPTH] = a3;
    }
}

// ---------------- Kernel 2: Wc_red[d][j] = sum_h Wc[h*64+d][j] ----------------
__global__ __launch_bounds__(256) void wcred_kernel(
    const float* __restrict__ Wc, float* __restrict__ Wr)
{
    int idx = blockIdx.x * 256 + threadIdx.x;
    if (idx >= DEPTH * DM) return;
    int d = idx / DM, j = idx % DM;
    float s = 0.f;
    #pragma unroll
    for (int h = 0; h < HH; ++h)
        s += Wc[(size_t)(h * DEPTH + d) * DM + j];
    Wr[idx] = s;
}

// --- Kernel 3: MFMA core with DEDICATED STORE WAVES (wid 8-11) for the weight burst ---
// 768 threads: waves 0-7 compute (r16 path, 21 LBARs), waves 8-11 sync to pf-ready
// (11 LBARs), stream 201MB of weight copies with NO subsequent load-waits, match
// the remaining 10 LBARs, exit. Per-wave vmcnt => compute waves never wait on stores.
__global__ __launch_bounds__(768, 6) void attn_core(
    const float* __restrict__ qh, const ushort* __restrict__ khu, const ushort* __restrict__ vhT,
    const float* __restrict__ Wr, const float* __restrict__ bc,
    float* __restrict__ out, float* __restrict__ attn)
{
    __shared__ __align__(16) ushort qf[16 * 72];         // Q bf16 (scaled), padded
    __shared__ __align__(16) ushort kvbuf[256 * 72];     // K stage / VT[64][264] / part+ohT
    __shared__ __align__(16) ushort pf[16 * 1032];       // P bf16, padded
    __shared__ float redmax[16 * 8];
    __shared__ float redsum[16 * 8];

    const int t = threadIdx.x, l = t & 63, wid = t >> 6;  // wid 0..11
    const int blk = blockIdx.x, b = blk >> 7;
    const int q0 = (blk & 127) * QBLK;

    if (wid < 8) {
        // ======================= COMPUTE WAVES (512 threads) =======================
        const int li = l & 15, g4 = l >> 4;
        const int key = t >> 1, hf = t & 1;              // K staging role

        // init: qf rows 0-7 = bf16(qh*scale); rows 8-15 = 0; pf rows 8-15 = 0
        {
            const int qq = t >> 6, dd = t & 63;
            qf[qq * 72 + dd] = f2bf(qh[((size_t)b * SS + q0 + qq) * DEPTH + dd] * 0.28867513459481287f);
            for (int i = t; i < 8 * 72; i += 512) qf[8 * 72 + i] = 0;
            for (int i = t; i < 8 * 1032; i += 512) pf[8 * 1032 + i] = 0;
        }

        const ushort* khb = khu + (size_t)b * SS * DEPTH;
        const ushort* vtb = vhT + (size_t)b * SS;        // + d*NROWS + col

        // prefetch K stage 0 (coalesced)
        uint4 kr0, kr1, kr2, kr3;
        {
            const uint4* g = (const uint4*)(khb + (size_t)key * DEPTH + hf * 32);
            kr0 = g[0]; kr1 = g[1]; kr2 = g[2]; kr3 = g[3];
        }
        LBAR();                                          // #1

        // A-frags (Q)
        const bf16x8 a0 = *(const bf16x8*)&qf[li * 72 + g4 * 8];
        const bf16x8 a1 = *(const bf16x8*)&qf[li * 72 + 32 + g4 * 8];

        f32x4 c[8];
        #pragma unroll
        for (int i = 0; i < 8; ++i) c[i] = (f32x4){0.f, 0.f, 0.f, 0.f};

        // ---- QK: 4 stages of 256 keys (LBARs #2-#8) ----
        #pragma unroll
        for (int s = 0; s < 4; ++s) {
            if (s) LBAR();
            {
                uint4* d4 = (uint4*)&kvbuf[key * 72 + hf * 32];
                d4[0] = kr0; d4[1] = kr1; d4[2] = kr2; d4[3] = kr3;
            }
            if (s < 3) {
                const uint4* g = (const uint4*)(khb + (size_t)((s + 1) * 256 + key) * DEPTH + hf * 32);
                kr0 = g[0]; kr1 = g[1]; kr2 = g[2]; kr3 = g[3];
            }
            LBAR();
            __builtin_amdgcn_s_setprio(1);
            #pragma unroll
            for (int jj = 0; jj < 2; ++jj) {
                const int tl = wid + 8 * jj;
                const int ci = 2 * s + jj;
                const bf16x8 b0 = *(const bf16x8*)&kvbuf[(tl * 16 + li) * 72 + g4 * 8];
                const bf16x8 b1 = *(const bf16x8*)&kvbuf[(tl * 16 + li) * 72 + 32 + g4 * 8];
                c[ci] = __builtin_amdgcn_mfma_f32_16x16x32_bf16(a0, b0, c[ci], 0, 0, 0);
                c[ci] = __builtin_amdgcn_mfma_f32_16x16x32_bf16(a1, b1, c[ci], 0, 0, 0);
            }
            __builtin_amdgcn_s_setprio(0);
        }

        // V staging roles: row vrow, 16B col
        const int vrow = t >> 5;                         // 0..15
        const int vcol = (t & 31) * 8;                   // ushort col, 16B aligned
        uint4 vp0, vp1, vp2, vp3;
        {
            vp0 = *(const uint4*)(vtb + (size_t)(0 * 16 + vrow) * NROWS + vcol);
            vp1 = *(const uint4*)(vtb + (size_t)(1 * 16 + vrow) * NROWS + vcol);
            vp2 = *(const uint4*)(vtb + (size_t)(2 * 16 + vrow) * NROWS + vcol);
            vp3 = *(const uint4*)(vtb + (size_t)(3 * 16 + vrow) * NROWS + vcol);
        }

        // ---- softmax on C-frags (LBARs #9,#10,#11) ----
        float mx[4], sm[4], inv[4];
        #pragma unroll
        for (int r = 0; r < 4; ++r) {
            float m_ = c[0][r];
            #pragma unroll
            for (int i = 1; i < 8; ++i) m_ = fmaxf(m_, c[i][r]);
            #pragma unroll
            for (int off = 1; off < 16; off <<= 1) m_ = fmaxf(m_, __shfl_xor(m_, off));
            mx[r] = m_;
        }
        if (li == 0) {
            #pragma unroll
            for (int r = 0; r < 4; ++r) redmax[(4 * g4 + r) * 8 + wid] = mx[r];
        }
        LBAR();                                          // #9
        #pragma unroll
        for (int r = 0; r < 4; ++r) {
            float m_ = redmax[(4 * g4 + r) * 8];
            #pragma unroll
            for (int w2 = 1; w2 < 8; ++w2) m_ = fmaxf(m_, redmax[(4 * g4 + r) * 8 + w2]);
            mx[r] = m_;
            sm[r] = 0.f;
        }
        #pragma unroll
        for (int i = 0; i < 8; ++i) {
            #pragma unroll
            for (int r = 0; r < 4; ++r) {
                const float e = __expf(c[i][r] - mx[r]);
                c[i][r] = e;
                sm[r] += e;
            }
        }
        #pragma unroll
        for (int r = 0; r < 4; ++r) {
            float s_ = sm[r];
            #pragma unroll
            for (int off = 1; off < 16; off <<= 1) s_ += __shfl_xor(s_, off);
            sm[r] = s_;
        }
        if (li == 0) {
            #pragma unroll
            for (int r = 0; r < 4; ++r) redsum[(4 * g4 + r) * 8 + wid] = sm[r];
        }
        LBAR();                                          // #10
        #pragma unroll
        for (int r = 0; r < 4; ++r) {
            float s_ = 0.f;
            #pragma unroll
            for (int w2 = 0; w2 < 8; ++w2) s_ += redsum[(4 * g4 + r) * 8 + w2];
            inv[r] = 1.f / s_;
        }
        if (l < 32) {
            #pragma unroll
            for (int i = 0; i < 8; ++i) {
                const int colbase = (16 * (i >> 1) + wid + 8 * (i & 1)) * 16 + li;
                #pragma unroll
                for (int r = 0; r < 4; ++r)
                    pf[(4 * g4 + r) * 1032 + colbase] = f2bf(c[i][r] * inv[r]);
            }
        }
        LBAR();                                          // #11  <- pf ready

        // ---- PV: 4 stages (LBARs #12-#18) ----
        f32x4 cp = {0.f, 0.f, 0.f, 0.f};
        const int dt = wid >> 1, par = wid & 1;
        ushort* VT = kvbuf;                              // [64][264]
        #pragma unroll
        for (int s = 0; s < 4; ++s) {
            if (s) LBAR();
            {
                *(uint4*)&VT[(0 * 16 + vrow) * 264 + vcol] = vp0;
                *(uint4*)&VT[(1 * 16 + vrow) * 264 + vcol] = vp1;
                *(uint4*)&VT[(2 * 16 + vrow) * 264 + vcol] = vp2;
                *(uint4*)&VT[(3 * 16 + vrow) * 264 + vcol] = vp3;
            }
            if (s < 3) {
                const int sc = (s + 1) * 256;
                vp0 = *(const uint4*)(vtb + (size_t)(0 * 16 + vrow) * NROWS + sc + vcol);
                vp1 = *(const uint4*)(vtb + (size_t)(1 * 16 + vrow) * NROWS + sc + vcol);
                vp2 = *(const uint4*)(vtb + (size_t)(2 * 16 + vrow) * NROWS + sc + vcol);
                vp3 = *(const uint4*)(vtb + (size_t)(3 * 16 + vrow) * NROWS + sc + vcol);
            }
            LBAR();
            __builtin_amdgcn_s_setprio(1);
            #pragma unroll
            for (int c2 = 0; c2 < 4; ++c2) {
                const int cc = par + 2 * c2;
                const bf16x8 ap = *(const bf16x8*)&pf[li * 1032 + s * 256 + cc * 32 + g4 * 8];
                const bf16x8 bv = *(const bf16x8*)&VT[(dt * 16 + li) * 264 + cc * 32 + g4 * 8];
                cp = __builtin_amdgcn_mfma_f32_16x16x32_bf16(ap, bv, cp, 0, 0, 0);
            }
            __builtin_amdgcn_s_setprio(0);
        }
        LBAR();                                          // #19

        // ---- reduce parity pairs -> ohT[64][12] (LBARs #20,#21) ----
        float* part_f = (float*)kvbuf;                   // [8][256]
        float* ohT_f  = ((float*)kvbuf) + 2048;          // [64][12]
        #pragma unroll
        for (int r = 0; r < 4; ++r) part_f[wid * 256 + r * 64 + l] = cp[r];
        LBAR();                                          // #20
        {
            const int qq = t >> 6, dd = t & 63;
            const int ls = (qq >> 2) * 16 + (dd & 15), rr = qq & 3, w0 = (dd >> 4) * 2;
            ohT_f[dd * 12 + qq] = part_f[w0 * 256 + rr * 64 + ls] + part_f[(w0 + 1) * 256 + rr * 64 + ls];
        }
        LBAR();                                          // #21

        // ---- out rows = ohT @ Wr + bc ----
        for (int j = t; j < DM; j += 512) {
            float a[QBLK];
            const float bj = bc[j];
            #pragma unroll
            for (int r = 0; r < QBLK; ++r) a[r] = bj;
            const float* wc = Wr + j;
            #pragma unroll 16
            for (int d2 = 0; d2 < DEPTH; ++d2) {
                const float wv = wc[(size_t)d2 * DM];
                const float4 o0 = *(const float4*)&ohT_f[d2 * 12];
                const float4 o1 = *(const float4*)&ohT_f[d2 * 12 + 4];
                a[0] = fmaf(o0.x, wv, a[0]); a[1] = fmaf(o0.y, wv, a[1]);
                a[2] = fmaf(o0.z, wv, a[2]); a[3] = fmaf(o0.w, wv, a[3]);
                a[4] = fmaf(o1.x, wv, a[4]); a[5] = fmaf(o1.y, wv, a[5]);
                a[6] = fmaf(o1.z, wv, a[6]); a[7] = fmaf(o1.w, wv, a[7]);
            }
            float* ob = out + ((size_t)b * SS + q0) * DM + j;
            #pragma unroll
            for (int r = 0; r < QBLK; ++r)
                __builtin_nontemporal_store(a[r], ob + (size_t)r * DM);
        }
    } else {
        // ======================= STORE WAVES (256 threads) =======================
        // match compute path's first 11 barriers (pf ready after #11)
        #pragma unroll
        for (int i = 0; i < 11; ++i) LBAR();

        const int ts = t - 512;                          // 0..255
        const int col = ts * 4;
        vfloat4 v[8];
        #pragma unroll
        for (int qq = 0; qq < 8; ++qq) {
            const ushort* prow = &pf[qq * 1032 + col];
            v[qq].x = __uint_as_float((uint)prow[0] << 16);
            v[qq].y = __uint_as_float((uint)prow[1] << 16);
            v[qq].z = __uint_as_float((uint)prow[2] << 16);
            v[qq].w = __uint_as_float((uint)prow[3] << 16);
        }
        // 96 nt-stores; NO load-wait ever follows on these waves -> true overlap
        float* abase = attn + ((size_t)(b * HH) * SS + q0) * SS + col;
        #pragma unroll
        for (int h = 0; h < HH; ++h) {
            float* hp = abase + (size_t)h * SS * SS;
            #pragma unroll
            for (int qq = 0; qq < 8; ++qq)
                __builtin_nontemporal_store(v[qq], (vfloat4*)(hp + (size_t)qq * SS));
        }

        // match remaining 10 barriers, then exit (stores drain independently)
        #pragma unroll
        for (int i = 0; i < 10; ++i) LBAR();
    }
}

extern "C" void kernel_launch(void* const* d_in, const int* in_sizes, int n_in,
                              void* d_out, int out_size, void* d_ws, size_t ws_size,
                              hipStream_t stream) {
    const float* q  = (const float*)d_in[0];
    const float* k  = (const float*)d_in[1];
    const float* v  = (const float*)d_in[2];
    const float* Wq = (const float*)d_in[3];
    const float* bq = (const float*)d_in[4];
    const float* Wk = (const float*)d_in[5];
    const float* bk = (const float*)d_in[6];
    const float* Wv = (const float*)d_in[7];
    const float* bv = (const float*)d_in[8];
    const float* Wc = (const float*)d_in[9];
    const float* bc = (const float*)d_in[10];

    float* out  = (float*)d_out;                              // [B,S,DM]
    float* attn = out + (size_t)BB * SS * DM;                 // [B,H,S,S]

    float* ws = (float*)d_ws;
    const size_t NPROJ = (size_t)NROWS * DEPTH;               // 262144
    float* qh   = ws;                                         // f32
    ushort* khu = (ushort*)(ws + NPROJ);                      // bf16 row-major
    ushort* vhT = (ushort*)(ws + NPROJ + NPROJ / 2);          // bf16 transposed [DEPTH][NROWS]
    float* Wr   = ws + 2 * NPROJ;                             // 64*768 f32

    wcred_kernel<<<(DEPTH * DM + 255) / 256, 256, 0, stream>>>(Wc, Wr);
    proj_kernel<<<3 * (NROWS / PROWS), 256, 0, stream>>>(q, k, v, Wq, bq, Wk, bk, Wv, bv, qh, khu, vhT);
    attn_core<<<BB * (SS / QBLK), 768, 0, stream>>>(qh, khu, vhT, Wr, bc, out, attn);
}